// Round 4
// baseline (2221.817 us; speedup 1.0000x reference)
//
#include <hip/hip_runtime.h>
#include <hip/hip_bf16.h>

#define FDIM 512
#define HDIM 256
#define CDIM 64
#define KSTEPS 10

#define RPB 128          // dst rows per spmv block
#define NQ 7             // source phases
#define QSH 14           // src >> 14 -> 0..6 (slices of 16384 rows = 2MB bf16)
#define KPB (NQ * RPB)   // keys per block = 896

typedef __attribute__((ext_vector_type(8))) short bf16x8;
typedef __attribute__((ext_vector_type(4))) float f32x4;

static __device__ __forceinline__ unsigned short f2bf(float f) {
  union { float f; unsigned int u; } x; x.f = f;
  unsigned int u = x.u;
  return (unsigned short)((u + 0x7fffu + ((u >> 16) & 1u)) >> 16);  // RNE
}
static __device__ __forceinline__ float bfhi2f(unsigned int u) {
  union { unsigned int u; float f; } x; x.u = u; return x.f;
}

// ---------------- weight prep: fp32 [K][N] -> bf16 transposed [N][K] -------
__global__ void prep_w(const float* __restrict__ W1, const float* __restrict__ W2,
                       unsigned short* __restrict__ W1t, unsigned short* __restrict__ W2t) {
  int i = blockIdx.x * 256 + threadIdx.x;
  if (i < FDIM * HDIM) { int k = i / HDIM, n = i % HDIM; W1t[(size_t)n * FDIM + k] = f2bf(W1[i]); }
  if (i < HDIM * CDIM) { int k = i / CDIM, n = i % CDIM; W2t[(size_t)n * HDIM + k] = f2bf(W2[i]); }
}

// ---------------- graph prep -----------------------------------------------
// key = (dstblock*NQ + srcphase)*RPB + (dst & 127)
__global__ void hist_k(const int* __restrict__ src, const int* __restrict__ dst,
                       int* __restrict__ hist, int E) {
  int i = blockIdx.x * 256 + threadIdx.x;
  if (i < E) {
    int s = src[i], d = dst[i];
    int k = ((d >> 7) * NQ + (s >> QSH)) * RPB + (d & 127);
    atomicAdd(&hist[k], 1);
  }
}

__global__ void scan_block(const int* __restrict__ deg, int* __restrict__ out,
                           int* __restrict__ bsum, int n) {
  __shared__ int tmp[1024];
  int i = blockIdx.x * 1024 + threadIdx.x;
  int v = (i < n) ? deg[i] : 0;
  tmp[threadIdx.x] = v;
  __syncthreads();
  for (int off = 1; off < 1024; off <<= 1) {
    int t = (threadIdx.x >= off) ? tmp[threadIdx.x - off] : 0;
    __syncthreads();
    tmp[threadIdx.x] += t;
    __syncthreads();
  }
  if (i < n) out[i] = tmp[threadIdx.x] - v;  // exclusive
  if (threadIdx.x == 1023) bsum[blockIdx.x] = tmp[1023];
}

__global__ void scan_sums(const int* __restrict__ bsum, int* __restrict__ boff, int nb) {
  if (threadIdx.x == 0 && blockIdx.x == 0) {
    int run = 0;
    for (int b = 0; b < nb; ++b) { boff[b] = run; run += bsum[b]; }
  }
}

__global__ void scan_add(int* __restrict__ rp2, int* __restrict__ cursor,
                         const int* __restrict__ boff, int n, int total) {
  int i = blockIdx.x * 1024 + threadIdx.x;
  if (i < n) {
    int v = rp2[i] + boff[blockIdx.x];
    rp2[i] = v;
    cursor[i] = v;
  }
  if (i == 0) rp2[n] = total;
}

// deg[r] = sum over q of sublist lengths; dinv = rsqrt(deg+1)
__global__ void dinv2_k(const int* __restrict__ rp2, float* __restrict__ dinv, int n) {
  int r = blockIdx.x * 256 + threadIdx.x;
  if (r < n) {
    int base = (r >> 7) * KPB + (r & 127);
    int d = 0;
#pragma unroll
    for (int q = 0; q < NQ; ++q) d += rp2[base + q * RPB + 1] - rp2[base + q * RPB];
    dinv[r] = rsqrtf((float)d + 1.0f);
  }
}

// packed 8B record per edge: {src, bitcast(dinv[src])}
__global__ void fill_k(const int* __restrict__ src, const int* __restrict__ dst,
                       const float* __restrict__ dinv, int* __restrict__ cursor,
                       uint2* __restrict__ edges, int E) {
  int i = blockIdx.x * 256 + threadIdx.x;
  if (i < E) {
    int s = src[i], d = dst[i];
    int k = ((d >> 7) * NQ + (s >> QSH)) * RPB + (d & 127);
    int p = atomicAdd(&cursor[k], 1);
    union { float f; unsigned int u; } w; w.f = dinv[s];
    uint2 rec; rec.x = (unsigned int)s; rec.y = w.u;
    edges[p] = rec;
  }
}

// ---------------- GEMM1: h1 = relu(x @ W1 + b1), tile 64(M) x 256(N=all) ---
__global__ __launch_bounds__(256) void gemm1_k(const float* __restrict__ A,
                                               const unsigned short* __restrict__ Bt,
                                               const float* __restrict__ bias,
                                               unsigned short* __restrict__ C, int M) {
  __shared__ unsigned short Al[64][40];
  __shared__ unsigned short Bl[256][40];
  const int tid = threadIdx.x;
  const int wid = tid >> 6;
  const int lane = tid & 63;
  const int m0 = blockIdx.x * 64;
  const int srow = tid >> 2;
  const int scg = (tid & 3) * 8;
  f32x4 acc[16];
#pragma unroll
  for (int i = 0; i < 16; ++i) acc[i] = (f32x4){0.f, 0.f, 0.f, 0.f};
  for (int k0 = 0; k0 < FDIM; k0 += 32) {
    {
      const int gr = m0 + srow;
      unsigned short av[8];
      if (gr < M) {
        const float* p = A + (size_t)gr * FDIM + k0 + scg;
#pragma unroll
        for (int j = 0; j < 8; ++j) av[j] = f2bf(p[j]);
      } else {
#pragma unroll
        for (int j = 0; j < 8; ++j) av[j] = 0;
      }
      *(bf16x8*)(&Al[srow][scg]) = *(bf16x8*)av;
    }
#pragma unroll
    for (int j = 0; j < 4; ++j) {
      const int br = srow + 64 * j;
      bf16x8 v = *(const bf16x8*)(Bt + (size_t)br * FDIM + k0 + scg);
      *(bf16x8*)(&Bl[br][scg]) = v;
    }
    __syncthreads();
    bf16x8 a = *(const bf16x8*)(&Al[wid * 16 + (lane & 15)][(lane >> 4) * 8]);
#pragma unroll
    for (int nf = 0; nf < 16; ++nf) {
      bf16x8 b = *(const bf16x8*)(&Bl[nf * 16 + (lane & 15)][(lane >> 4) * 8]);
      acc[nf] = __builtin_amdgcn_mfma_f32_16x16x32_bf16(a, b, acc[nf], 0, 0, 0);
    }
    __syncthreads();
  }
#pragma unroll
  for (int nf = 0; nf < 16; ++nf) {
    const int colg = nf * 16 + (lane & 15);
    const float bb = bias[colg];
#pragma unroll
    for (int r = 0; r < 4; ++r) {
      const int rowg = m0 + wid * 16 + (lane >> 4) * 4 + r;
      if (rowg < M) {
        float v = fmaxf(acc[nf][r] + bb, 0.0f);
        C[(size_t)rowg * HDIM + colg] = f2bf(v);
      }
    }
  }
}

// ---------------- GEMM2: h0 = h1 @ W2 + b2 -> bf16, tile 64x64 -------------
__global__ __launch_bounds__(256) void gemm2_k(const unsigned short* __restrict__ A,
                                               const unsigned short* __restrict__ Bt,
                                               const float* __restrict__ bias,
                                               unsigned short* __restrict__ C, int M) {
  __shared__ unsigned short Al[64][40];
  __shared__ unsigned short Bl[64][40];
  const int tid = threadIdx.x;
  const int wid = tid >> 6;
  const int lane = tid & 63;
  const int m0 = blockIdx.x * 64;
  const int srow = tid >> 2;
  const int scg = (tid & 3) * 8;
  f32x4 acc[4];
#pragma unroll
  for (int i = 0; i < 4; ++i) acc[i] = (f32x4){0.f, 0.f, 0.f, 0.f};
  for (int k0 = 0; k0 < HDIM; k0 += 32) {
    {
      const int gr = m0 + srow;
      if (gr < M) {
        bf16x8 v = *(const bf16x8*)(A + (size_t)gr * HDIM + k0 + scg);
        *(bf16x8*)(&Al[srow][scg]) = v;
      } else {
        bf16x8 z = {0, 0, 0, 0, 0, 0, 0, 0};
        *(bf16x8*)(&Al[srow][scg]) = z;
      }
    }
    {
      bf16x8 v = *(const bf16x8*)(Bt + (size_t)srow * HDIM + k0 + scg);
      *(bf16x8*)(&Bl[srow][scg]) = v;
    }
    __syncthreads();
    bf16x8 a = *(const bf16x8*)(&Al[wid * 16 + (lane & 15)][(lane >> 4) * 8]);
#pragma unroll
    for (int nf = 0; nf < 4; ++nf) {
      bf16x8 b = *(const bf16x8*)(&Bl[nf * 16 + (lane & 15)][(lane >> 4) * 8]);
      acc[nf] = __builtin_amdgcn_mfma_f32_16x16x32_bf16(a, b, acc[nf], 0, 0, 0);
    }
    __syncthreads();
  }
#pragma unroll
  for (int nf = 0; nf < 4; ++nf) {
    const int colg = nf * 16 + (lane & 15);
    const float bb = bias[colg];
#pragma unroll
    for (int r = 0; r < 4; ++r) {
      const int rowg = m0 + wid * 16 + (lane >> 4) * 4 + r;
      if (rowg < M) C[(size_t)rowg * CDIM + colg] = f2bf(acc[nf][r] + bb);
    }
  }
}

// ---------------- APPNP step: source-sliced, LDS-accumulated ---------------
// Block owns 128 dst rows; fp32 acc[128][64] in LDS. 7 source phases swept by
// all (co-resident) blocks in approx lockstep -> 2MB hin slice is L2-resident.
// Wave w owns rows [w*32, w*32+32); slot s (16 lanes) exclusively owns rows
// rl = w*32 + 4j + s -> no cross-slot reduce, one LDS RMW per (row,phase).
__global__ __launch_bounds__(256) void spmv_k(const int* __restrict__ rp2,
                                              const uint2* __restrict__ edges,
                                              const float* __restrict__ dinv,
                                              const unsigned short* __restrict__ hin,
                                              const unsigned short* __restrict__ h0,
                                              unsigned short* __restrict__ hout, int n) {
  __shared__ float acc[RPB][CDIM];  // 32 KB
  const int tid = threadIdx.x;
  {
    f32x4* p = (f32x4*)&acc[0][0];
#pragma unroll
    for (int i = 0; i < 8; ++i) p[tid + 256 * i] = (f32x4){0.f, 0.f, 0.f, 0.f};
  }
  __syncthreads();
  const int w = tid >> 6;
  const int lane = tid & 63;
  const int s = lane >> 4;
  const int ch = (lane & 15) * 4;   // 4 bf16 channels = 8B
  const int b = blockIdx.x;
  const int kb = b * KPB;
  for (int q = 0; q < NQ; ++q) {
#pragma unroll
    for (int j = 0; j < 8; ++j) {
      const int rl = w * 32 + 4 * j + s;
      const int k = kb + q * RPB + rl;
      int e = rp2[k];
      const int e1 = rp2[k + 1];
      float a0 = 0.f, a1 = 0.f, a2 = 0.f, a3 = 0.f;
      for (; e + 1 < e1; e += 2) {
        const uint2 r0 = edges[e];
        const uint2 r1 = edges[e + 1];
        const uint2 v0 = *(const uint2*)(hin + (size_t)r0.x * 64 + ch);
        const uint2 v1 = *(const uint2*)(hin + (size_t)r1.x * 64 + ch);
        const float w0 = bfhi2f(r0.y), w1 = bfhi2f(r1.y);
        a0 += w0 * bfhi2f(v0.x << 16) + w1 * bfhi2f(v1.x << 16);
        a1 += w0 * bfhi2f(v0.x & 0xffff0000u) + w1 * bfhi2f(v1.x & 0xffff0000u);
        a2 += w0 * bfhi2f(v0.y << 16) + w1 * bfhi2f(v1.y << 16);
        a3 += w0 * bfhi2f(v0.y & 0xffff0000u) + w1 * bfhi2f(v1.y & 0xffff0000u);
      }
      if (e < e1) {
        const uint2 r0 = edges[e];
        const uint2 v0 = *(const uint2*)(hin + (size_t)r0.x * 64 + ch);
        const float w0 = bfhi2f(r0.y);
        a0 += w0 * bfhi2f(v0.x << 16);
        a1 += w0 * bfhi2f(v0.x & 0xffff0000u);
        a2 += w0 * bfhi2f(v0.y << 16);
        a3 += w0 * bfhi2f(v0.y & 0xffff0000u);
      }
      // exclusive-owner LDS RMW (converged across slots)
      f32x4 cv = *(f32x4*)&acc[rl][ch];
      cv[0] += a0; cv[1] += a1; cv[2] += a2; cv[3] += a3;
      *(f32x4*)&acc[rl][ch] = cv;
    }
  }
  // finalize: wave reads only its own rows -> no barrier needed
#pragma unroll
  for (int it = 0; it < 8; ++it) {
    const int rl = w * 32 + it * 4 + (lane >> 4);
    const int r = b * RPB + rl;
    if (r < n) {
      const int c2 = (lane & 15) * 4;
      const f32x4 av = *(f32x4*)&acc[rl][c2];
      const float di = dinv[r];
      const float dii = di * di;
      const uint2 hs = *(const uint2*)(hin + (size_t)r * 64 + c2);
      const uint2 hz = *(const uint2*)(h0 + (size_t)r * 64 + c2);
      const float o0 = 0.9f * (di * av[0] + dii * bfhi2f(hs.x << 16)) + 0.1f * bfhi2f(hz.x << 16);
      const float o1 = 0.9f * (di * av[1] + dii * bfhi2f(hs.x & 0xffff0000u)) + 0.1f * bfhi2f(hz.x & 0xffff0000u);
      const float o2 = 0.9f * (di * av[2] + dii * bfhi2f(hs.y << 16)) + 0.1f * bfhi2f(hz.y << 16);
      const float o3 = 0.9f * (di * av[3] + dii * bfhi2f(hs.y & 0xffff0000u)) + 0.1f * bfhi2f(hz.y & 0xffff0000u);
      uint2 pk;
      pk.x = ((unsigned int)f2bf(o1) << 16) | f2bf(o0);
      pk.y = ((unsigned int)f2bf(o3) << 16) | f2bf(o2);
      *(uint2*)(hout + (size_t)r * 64 + c2) = pk;
    }
  }
}

// ---------------- log_softmax over 64 classes (bf16 in, fp32 out) ----------
__global__ __launch_bounds__(256) void logsoftmax_k(const unsigned short* __restrict__ h,
                                                    float* __restrict__ out, int n) {
  const int r = blockIdx.x * 4 + (threadIdx.x >> 6);
  if (r >= n) return;
  const int lane = threadIdx.x & 63;
  float v = bfhi2f(((unsigned int)h[(size_t)r * 64 + lane]) << 16);
  float m = v;
#pragma unroll
  for (int o = 32; o; o >>= 1) m = fmaxf(m, __shfl_xor(m, o, 64));
  float ex = expf(v - m);
  float s = ex;
#pragma unroll
  for (int o = 32; o; o >>= 1) s += __shfl_xor(s, o, 64);
  out[(size_t)r * 64 + lane] = v - m - logf(s);
}

extern "C" void kernel_launch(void* const* d_in, const int* in_sizes, int n_in,
                              void* d_out, int out_size, void* d_ws, size_t ws_size,
                              hipStream_t stream) {
  const float* x = (const float*)d_in[0];
  const float* W1 = (const float*)d_in[1];
  const float* b1 = (const float*)d_in[2];
  const float* W2 = (const float*)d_in[3];
  const float* b2 = (const float*)d_in[4];
  const int* ei = (const int*)d_in[5];
  const int E = in_sizes[5] / 2;
  const int N = in_sizes[0] / FDIM;
  const int* src = ei;
  const int* dst = ei + E;

  const int NBLK = (N + RPB - 1) / RPB;   // 782
  const int KR = NBLK * KPB;              // 700672 keys

  char* wp = (char*)d_ws;
  auto alloc = [&](size_t b) {
    char* p = wp;
    wp += (b + 255) & ~(size_t)255;
    return p;
  };
  unsigned short* W1t = (unsigned short*)alloc((size_t)HDIM * FDIM * 2);
  unsigned short* W2t = (unsigned short*)alloc((size_t)CDIM * HDIM * 2);
  unsigned short* h1 = (unsigned short*)alloc((size_t)N * HDIM * 2);
  unsigned short* hb0 = (unsigned short*)alloc((size_t)N * CDIM * 2);
  unsigned short* hA = (unsigned short*)alloc((size_t)N * CDIM * 2);
  unsigned short* hB = (unsigned short*)alloc((size_t)N * CDIM * 2);
  int* hist = (int*)alloc((size_t)KR * 4);
  int* rp2 = (int*)alloc((size_t)(KR + 1) * 4);
  int* cursor = (int*)alloc((size_t)KR * 4);
  float* dinv = (float*)alloc((size_t)N * 4);
  int* bsum = (int*)alloc(4096);
  int* boff = (int*)alloc(4096);
  uint2* edges = (uint2*)alloc((size_t)E * 8);

  // weight prep
  prep_w<<<(FDIM * HDIM + 255) / 256, 256, 0, stream>>>(W1, W2, W1t, W2t);

  // graph prep: histogram over (dstblock, srcphase, dstlow) keys -> scan -> fill
  hipMemsetAsync(hist, 0, (size_t)KR * 4, stream);
  hist_k<<<(E + 255) / 256, 256, 0, stream>>>(src, dst, hist, E);
  const int nb = (KR + 1023) >> 10;
  scan_block<<<nb, 1024, 0, stream>>>(hist, rp2, bsum, KR);
  scan_sums<<<1, 64, 0, stream>>>(bsum, boff, nb);
  scan_add<<<nb, 1024, 0, stream>>>(rp2, cursor, boff, KR, E);
  dinv2_k<<<(N + 255) / 256, 256, 0, stream>>>(rp2, dinv, N);
  fill_k<<<(E + 255) / 256, 256, 0, stream>>>(src, dst, dinv, cursor, edges, E);

  // MLP
  gemm1_k<<<(N + 63) / 64, 256, 0, stream>>>(x, W1t, b1, h1, N);
  gemm2_k<<<(N + 63) / 64, 256, 0, stream>>>(h1, W2t, b2, hb0, N);

  // APPNP propagation (10 steps, ping-pong, bf16 state)
  const unsigned short* cur = hb0;
  unsigned short* bufs[2] = {hA, hB};
  for (int t = 0; t < KSTEPS; ++t) {
    unsigned short* outb = bufs[t & 1];
    spmv_k<<<NBLK, 256, 0, stream>>>(rp2, edges, dinv, cur, hb0, outb, N);
    cur = outb;
  }

  // log_softmax -> d_out (fp32)
  logsoftmax_k<<<(N + 3) / 4, 256, 0, stream>>>(cur, (float*)d_out, N);
}

// Round 5
// 1494.451 us; speedup vs baseline: 1.4867x; 1.4867x over previous
//
#include <hip/hip_runtime.h>
#include <hip/hip_bf16.h>

#define FDIM 512
#define HDIM 256
#define CDIM 64
#define KSTEPS 10

#define RPB 128          // dst rows per spmv block
#define NQ 7             // source phases (slices of 16384 rows = 2MB bf16)
#define QSH 14
#define KPB (NQ * 16)    // keys per block = 112  (key sub-index = dst&15)

typedef __attribute__((ext_vector_type(8))) short bf16x8;
typedef __attribute__((ext_vector_type(4))) float f32x4;

static __device__ __forceinline__ unsigned short f2bf(float f) {
  union { float f; unsigned int u; } x; x.f = f;
  unsigned int u = x.u;
  return (unsigned short)((u + 0x7fffu + ((u >> 16) & 1u)) >> 16);  // RNE
}
static __device__ __forceinline__ float bfhi2f(unsigned int u) {
  union { unsigned int u; float f; } x; x.u = u; return x.f;
}

// ---------------- weight prep: fp32 [K][N] -> bf16 transposed [N][K] -------
__global__ void prep_w(const float* __restrict__ W1, const float* __restrict__ W2,
                       unsigned short* __restrict__ W1t, unsigned short* __restrict__ W2t) {
  int i = blockIdx.x * 256 + threadIdx.x;
  if (i < FDIM * HDIM) { int k = i / HDIM, n = i % HDIM; W1t[(size_t)n * FDIM + k] = f2bf(W1[i]); }
  if (i < HDIM * CDIM) { int k = i / CDIM, n = i % CDIM; W2t[(size_t)n * HDIM + k] = f2bf(W2[i]); }
}

// ---------------- graph prep -----------------------------------------------
// key = (dstblock*NQ + srcphase)*16 + (dst & 15)
__global__ void hd_k(const int* __restrict__ src, const int* __restrict__ dst,
                     int* __restrict__ deg, int* __restrict__ hist, int E) {
  int i = blockIdx.x * 256 + threadIdx.x;
  if (i < E) {
    int s = src[i], d = dst[i];
    atomicAdd(&deg[d], 1);
    int k = ((d >> 7) * NQ + (s >> QSH)) * 16 + (d & 15);
    atomicAdd(&hist[k], 1);
  }
}

// dinv, 0.9*dinv^2, sqrt(deg+1)
__global__ void dinv3_k(const int* __restrict__ deg, float* __restrict__ dinv,
                        float* __restrict__ dii9, float* __restrict__ dsq, int n) {
  int r = blockIdx.x * 256 + threadIdx.x;
  if (r < n) {
    float dp1 = (float)deg[r] + 1.0f;
    float di = rsqrtf(dp1);
    dinv[r] = di;
    dii9[r] = 0.9f * di * di;
    dsq[r] = sqrtf(dp1);
  }
}

__global__ void scan_block(const int* __restrict__ in, int* __restrict__ out,
                           int* __restrict__ bsum, int n) {
  __shared__ int tmp[1024];
  int i = blockIdx.x * 1024 + threadIdx.x;
  int v = (i < n) ? in[i] : 0;
  tmp[threadIdx.x] = v;
  __syncthreads();
  for (int off = 1; off < 1024; off <<= 1) {
    int t = (threadIdx.x >= off) ? tmp[threadIdx.x - off] : 0;
    __syncthreads();
    tmp[threadIdx.x] += t;
    __syncthreads();
  }
  if (i < n) out[i] = tmp[threadIdx.x] - v;  // exclusive
  if (threadIdx.x == 1023) bsum[blockIdx.x] = tmp[1023];
}

// parallel scan of block sums (nb <= 1024), single block
__global__ void scan_sums_par(const int* __restrict__ bsum, int* __restrict__ boff, int nb) {
  __shared__ int tmp[1024];
  int t = threadIdx.x;
  int v = (t < nb) ? bsum[t] : 0;
  tmp[t] = v;
  __syncthreads();
  for (int off = 1; off < 1024; off <<= 1) {
    int x = (t >= off) ? tmp[t - off] : 0;
    __syncthreads();
    tmp[t] += x;
    __syncthreads();
  }
  if (t < nb) boff[t] = tmp[t] - v;  // exclusive
}

__global__ void scan_add(int* __restrict__ rp2, int* __restrict__ cursor,
                         const int* __restrict__ boff, int n, int total) {
  int i = blockIdx.x * 1024 + threadIdx.x;
  if (i < n) {
    int v = rp2[i] + boff[blockIdx.x];
    rp2[i] = v;
    cursor[i] = v;
  }
  if (i == 0) rp2[n] = total;
}

// 4B record: src | ((dst>>4)&7) << 17
__global__ void fill2_k(const int* __restrict__ src, const int* __restrict__ dst,
                        int* __restrict__ cursor, unsigned int* __restrict__ edges, int E) {
  int i = blockIdx.x * 256 + threadIdx.x;
  if (i < E) {
    int s = src[i], d = dst[i];
    int k = ((d >> 7) * NQ + (s >> QSH)) * 16 + (d & 15);
    int p = atomicAdd(&cursor[k], 1);
    edges[p] = (unsigned int)s | (((unsigned int)(d >> 4) & 7u) << 17);
  }
}

// ---------------- GEMM1: h1 = relu(x @ W1 + b1), tile 64(M) x 256(N=all) ---
__global__ __launch_bounds__(256) void gemm1_k(const float* __restrict__ A,
                                               const unsigned short* __restrict__ Bt,
                                               const float* __restrict__ bias,
                                               unsigned short* __restrict__ C, int M) {
  __shared__ unsigned short Al[64][40];
  __shared__ unsigned short Bl[256][40];
  const int tid = threadIdx.x;
  const int wid = tid >> 6;
  const int lane = tid & 63;
  const int m0 = blockIdx.x * 64;
  const int srow = tid >> 2;
  const int scg = (tid & 3) * 8;
  f32x4 acc[16];
#pragma unroll
  for (int i = 0; i < 16; ++i) acc[i] = (f32x4){0.f, 0.f, 0.f, 0.f};
  for (int k0 = 0; k0 < FDIM; k0 += 32) {
    {
      const int gr = m0 + srow;
      unsigned short av[8];
      if (gr < M) {
        const float* p = A + (size_t)gr * FDIM + k0 + scg;
#pragma unroll
        for (int j = 0; j < 8; ++j) av[j] = f2bf(p[j]);
      } else {
#pragma unroll
        for (int j = 0; j < 8; ++j) av[j] = 0;
      }
      *(bf16x8*)(&Al[srow][scg]) = *(bf16x8*)av;
    }
#pragma unroll
    for (int j = 0; j < 4; ++j) {
      const int br = srow + 64 * j;
      bf16x8 v = *(const bf16x8*)(Bt + (size_t)br * FDIM + k0 + scg);
      *(bf16x8*)(&Bl[br][scg]) = v;
    }
    __syncthreads();
    bf16x8 a = *(const bf16x8*)(&Al[wid * 16 + (lane & 15)][(lane >> 4) * 8]);
#pragma unroll
    for (int nf = 0; nf < 16; ++nf) {
      bf16x8 b = *(const bf16x8*)(&Bl[nf * 16 + (lane & 15)][(lane >> 4) * 8]);
      acc[nf] = __builtin_amdgcn_mfma_f32_16x16x32_bf16(a, b, acc[nf], 0, 0, 0);
    }
    __syncthreads();
  }
#pragma unroll
  for (int nf = 0; nf < 16; ++nf) {
    const int colg = nf * 16 + (lane & 15);
    const float bb = bias[colg];
#pragma unroll
    for (int r = 0; r < 4; ++r) {
      const int rowg = m0 + wid * 16 + (lane >> 4) * 4 + r;
      if (rowg < M) {
        float v = fmaxf(acc[nf][r] + bb, 0.0f);
        C[(size_t)rowg * HDIM + colg] = f2bf(v);
      }
    }
  }
}

// ---------------- GEMM2: h0 = h1 @ W2 + b2 -> hb0 (bf16 h0) + g0 (bf16 dinv*h0)
__global__ __launch_bounds__(256) void gemm2g_k(const unsigned short* __restrict__ A,
                                                const unsigned short* __restrict__ Bt,
                                                const float* __restrict__ bias,
                                                const float* __restrict__ dinv,
                                                unsigned short* __restrict__ Hb0,
                                                unsigned short* __restrict__ G0, int M) {
  __shared__ unsigned short Al[64][40];
  __shared__ unsigned short Bl[64][40];
  const int tid = threadIdx.x;
  const int wid = tid >> 6;
  const int lane = tid & 63;
  const int m0 = blockIdx.x * 64;
  const int srow = tid >> 2;
  const int scg = (tid & 3) * 8;
  f32x4 acc[4];
#pragma unroll
  for (int i = 0; i < 4; ++i) acc[i] = (f32x4){0.f, 0.f, 0.f, 0.f};
  for (int k0 = 0; k0 < HDIM; k0 += 32) {
    {
      const int gr = m0 + srow;
      if (gr < M) {
        bf16x8 v = *(const bf16x8*)(A + (size_t)gr * HDIM + k0 + scg);
        *(bf16x8*)(&Al[srow][scg]) = v;
      } else {
        bf16x8 z = {0, 0, 0, 0, 0, 0, 0, 0};
        *(bf16x8*)(&Al[srow][scg]) = z;
      }
    }
    {
      bf16x8 v = *(const bf16x8*)(Bt + (size_t)srow * HDIM + k0 + scg);
      *(bf16x8*)(&Bl[srow][scg]) = v;
    }
    __syncthreads();
    bf16x8 a = *(const bf16x8*)(&Al[wid * 16 + (lane & 15)][(lane >> 4) * 8]);
#pragma unroll
    for (int nf = 0; nf < 4; ++nf) {
      bf16x8 b = *(const bf16x8*)(&Bl[nf * 16 + (lane & 15)][(lane >> 4) * 8]);
      acc[nf] = __builtin_amdgcn_mfma_f32_16x16x32_bf16(a, b, acc[nf], 0, 0, 0);
    }
    __syncthreads();
  }
#pragma unroll
  for (int nf = 0; nf < 4; ++nf) {
    const int colg = nf * 16 + (lane & 15);
    const float bb = bias[colg];
#pragma unroll
    for (int r = 0; r < 4; ++r) {
      const int rowg = m0 + wid * 16 + (lane >> 4) * 4 + r;
      if (rowg < M) {
        float v = acc[nf][r] + bb;
        Hb0[(size_t)rowg * CDIM + colg] = f2bf(v);
        G0[(size_t)rowg * CDIM + colg] = f2bf(dinv[rowg] * v);
      }
    }
  }
}

// ---------------- APPNP step: phase-sliced flat sublists, LDS accumulate ---
// state g = dinv*h (bf16).  g' = dii9[r]*(S_r + g[r]) + 0.1*dinv[r]*h0[r]
// group g(0..15) owns rows rl with rl&15==g; per (phase) a flat ~37-edge list.
__global__ __launch_bounds__(256) void spmv2_k(const int* __restrict__ rp2,
                                               const unsigned int* __restrict__ edges,
                                               const float* __restrict__ dii9,
                                               const float* __restrict__ dinv,
                                               const unsigned short* __restrict__ hb0,
                                               const unsigned short* __restrict__ hin,
                                               unsigned short* __restrict__ hout, int n) {
  __shared__ float acc[RPB][CDIM];  // 32 KB
  const int tid = threadIdx.x;
  {
    f32x4* p = (f32x4*)&acc[0][0];
#pragma unroll
    for (int i = 0; i < 8; ++i) p[tid + 256 * i] = (f32x4){0.f, 0.f, 0.f, 0.f};
  }
  __syncthreads();
  const int g = tid >> 4;           // group 0..15
  const int ch = (tid & 15) * 4;    // 4 bf16 channels = 8B
  const int kb = blockIdx.x * KPB + g;
  for (int q = 0; q < NQ; ++q) {
    const int k = kb + q * 16;
    int e = rp2[k];
    const int e1 = rp2[k + 1];
    for (; e + 3 < e1; e += 4) {
      const unsigned int r0 = edges[e], r1 = edges[e + 1];
      const unsigned int r2 = edges[e + 2], r3 = edges[e + 3];
      const uint2 v0 = *(const uint2*)(hin + (size_t)(r0 & 0x1FFFFu) * 64 + ch);
      const uint2 v1 = *(const uint2*)(hin + (size_t)(r1 & 0x1FFFFu) * 64 + ch);
      const uint2 v2 = *(const uint2*)(hin + (size_t)(r2 & 0x1FFFFu) * 64 + ch);
      const uint2 v3 = *(const uint2*)(hin + (size_t)(r3 & 0x1FFFFu) * 64 + ch);
      {
        const int rl = (int)((r0 >> 17) << 4) | g;
        f32x4 c = *(f32x4*)&acc[rl][ch];
        c[0] += bfhi2f(v0.x << 16); c[1] += bfhi2f(v0.x & 0xffff0000u);
        c[2] += bfhi2f(v0.y << 16); c[3] += bfhi2f(v0.y & 0xffff0000u);
        *(f32x4*)&acc[rl][ch] = c;
      }
      {
        const int rl = (int)((r1 >> 17) << 4) | g;
        f32x4 c = *(f32x4*)&acc[rl][ch];
        c[0] += bfhi2f(v1.x << 16); c[1] += bfhi2f(v1.x & 0xffff0000u);
        c[2] += bfhi2f(v1.y << 16); c[3] += bfhi2f(v1.y & 0xffff0000u);
        *(f32x4*)&acc[rl][ch] = c;
      }
      {
        const int rl = (int)((r2 >> 17) << 4) | g;
        f32x4 c = *(f32x4*)&acc[rl][ch];
        c[0] += bfhi2f(v2.x << 16); c[1] += bfhi2f(v2.x & 0xffff0000u);
        c[2] += bfhi2f(v2.y << 16); c[3] += bfhi2f(v2.y & 0xffff0000u);
        *(f32x4*)&acc[rl][ch] = c;
      }
      {
        const int rl = (int)((r3 >> 17) << 4) | g;
        f32x4 c = *(f32x4*)&acc[rl][ch];
        c[0] += bfhi2f(v3.x << 16); c[1] += bfhi2f(v3.x & 0xffff0000u);
        c[2] += bfhi2f(v3.y << 16); c[3] += bfhi2f(v3.y & 0xffff0000u);
        *(f32x4*)&acc[rl][ch] = c;
      }
    }
    for (; e < e1; ++e) {
      const unsigned int r0 = edges[e];
      const uint2 v0 = *(const uint2*)(hin + (size_t)(r0 & 0x1FFFFu) * 64 + ch);
      const int rl = (int)((r0 >> 17) << 4) | g;
      f32x4 c = *(f32x4*)&acc[rl][ch];
      c[0] += bfhi2f(v0.x << 16); c[1] += bfhi2f(v0.x & 0xffff0000u);
      c[2] += bfhi2f(v0.y << 16); c[3] += bfhi2f(v0.y & 0xffff0000u);
      *(f32x4*)&acc[rl][ch] = c;
    }
  }
  __syncthreads();
  // finalize
  const int w = tid >> 6;
  const int lane = tid & 63;
#pragma unroll
  for (int it = 0; it < 8; ++it) {
    const int rl = w * 32 + it * 4 + (lane >> 4);
    const int r = blockIdx.x * RPB + rl;
    if (r < n) {
      const f32x4 av = *(f32x4*)&acc[rl][ch];
      const float d9 = dii9[r];
      const float tp = 0.1f * dinv[r];
      const uint2 gs = *(const uint2*)(hin + (size_t)r * 64 + ch);
      const uint2 hz = *(const uint2*)(hb0 + (size_t)r * 64 + ch);
      const float o0 = d9 * (av[0] + bfhi2f(gs.x << 16)) + tp * bfhi2f(hz.x << 16);
      const float o1 = d9 * (av[1] + bfhi2f(gs.x & 0xffff0000u)) + tp * bfhi2f(hz.x & 0xffff0000u);
      const float o2 = d9 * (av[2] + bfhi2f(gs.y << 16)) + tp * bfhi2f(hz.y << 16);
      const float o3 = d9 * (av[3] + bfhi2f(gs.y & 0xffff0000u)) + tp * bfhi2f(hz.y & 0xffff0000u);
      uint2 pk;
      pk.x = ((unsigned int)f2bf(o1) << 16) | f2bf(o0);
      pk.y = ((unsigned int)f2bf(o3) << 16) | f2bf(o2);
      *(uint2*)(hout + (size_t)r * 64 + ch) = pk;
    }
  }
}

// ---------------- log_softmax over 64 classes (g_K bf16 in, fp32 out) ------
__global__ __launch_bounds__(256) void logsoftmax_k(const unsigned short* __restrict__ h,
                                                    const float* __restrict__ dsq,
                                                    float* __restrict__ out, int n) {
  const int r = blockIdx.x * 4 + (threadIdx.x >> 6);
  if (r >= n) return;
  const int lane = threadIdx.x & 63;
  float v = bfhi2f(((unsigned int)h[(size_t)r * 64 + lane]) << 16) * dsq[r];
  float m = v;
#pragma unroll
  for (int o = 32; o; o >>= 1) m = fmaxf(m, __shfl_xor(m, o, 64));
  float ex = expf(v - m);
  float s = ex;
#pragma unroll
  for (int o = 32; o; o >>= 1) s += __shfl_xor(s, o, 64);
  out[(size_t)r * 64 + lane] = v - m - logf(s);
}

extern "C" void kernel_launch(void* const* d_in, const int* in_sizes, int n_in,
                              void* d_out, int out_size, void* d_ws, size_t ws_size,
                              hipStream_t stream) {
  const float* x = (const float*)d_in[0];
  const float* W1 = (const float*)d_in[1];
  const float* b1 = (const float*)d_in[2];
  const float* W2 = (const float*)d_in[3];
  const float* b2 = (const float*)d_in[4];
  const int* ei = (const int*)d_in[5];
  const int E = in_sizes[5] / 2;
  const int N = in_sizes[0] / FDIM;
  const int* src = ei;
  const int* dst = ei + E;

  const int NBLK = (N + RPB - 1) / RPB;   // 782
  const int KR = NBLK * KPB;              // 87584 keys

  char* wp = (char*)d_ws;
  auto alloc = [&](size_t b) {
    char* p = wp;
    wp += (b + 255) & ~(size_t)255;
    return p;
  };
  unsigned short* W1t = (unsigned short*)alloc((size_t)HDIM * FDIM * 2);
  unsigned short* W2t = (unsigned short*)alloc((size_t)CDIM * HDIM * 2);
  unsigned short* h1 = (unsigned short*)alloc((size_t)N * HDIM * 2);
  unsigned short* hb0 = (unsigned short*)alloc((size_t)N * CDIM * 2);
  unsigned short* g0 = (unsigned short*)alloc((size_t)N * CDIM * 2);
  unsigned short* hA = (unsigned short*)alloc((size_t)N * CDIM * 2);
  unsigned short* hB = (unsigned short*)alloc((size_t)N * CDIM * 2);
  int* deg = (int*)alloc((size_t)N * 4);
  int* hist = (int*)alloc((size_t)KR * 4);
  int* rp2 = (int*)alloc((size_t)(KR + 1) * 4);
  int* cursor = (int*)alloc((size_t)KR * 4);
  float* dinv = (float*)alloc((size_t)N * 4);
  float* dii9 = (float*)alloc((size_t)N * 4);
  float* dsq = (float*)alloc((size_t)N * 4);
  int* bsum = (int*)alloc(4096);
  int* boff = (int*)alloc(4096);
  unsigned int* edges = (unsigned int*)alloc((size_t)E * 4);

  // weight prep
  prep_w<<<(FDIM * HDIM + 255) / 256, 256, 0, stream>>>(W1, W2, W1t, W2t);

  // graph prep
  hipMemsetAsync(deg, 0, (size_t)N * 4, stream);
  hipMemsetAsync(hist, 0, (size_t)KR * 4, stream);
  hd_k<<<(E + 255) / 256, 256, 0, stream>>>(src, dst, deg, hist, E);
  dinv3_k<<<(N + 255) / 256, 256, 0, stream>>>(deg, dinv, dii9, dsq, N);
  const int nb = (KR + 1023) >> 10;       // 86
  scan_block<<<nb, 1024, 0, stream>>>(hist, rp2, bsum, KR);
  scan_sums_par<<<1, 1024, 0, stream>>>(bsum, boff, nb);
  scan_add<<<nb, 1024, 0, stream>>>(rp2, cursor, boff, KR, E);
  fill2_k<<<(E + 255) / 256, 256, 0, stream>>>(src, dst, cursor, edges, E);

  // MLP
  gemm1_k<<<(N + 63) / 64, 256, 0, stream>>>(x, W1t, b1, h1, N);
  gemm2g_k<<<(N + 63) / 64, 256, 0, stream>>>(h1, W2t, b2, dinv, hb0, g0, N);

  // APPNP propagation in g-space (10 steps, ping-pong)
  const unsigned short* cur = g0;
  unsigned short* bufs[2] = {hA, hB};
  for (int t = 0; t < KSTEPS; ++t) {
    unsigned short* outb = bufs[t & 1];
    spmv2_k<<<NBLK, 256, 0, stream>>>(rp2, edges, dii9, dinv, hb0, cur, outb, N);
    cur = outb;
  }

  // log_softmax (rescale g -> h) -> d_out (fp32)
  logsoftmax_k<<<(N + 3) / 4, 256, 0, stream>>>(cur, dsq, (float*)d_out, N);
}